// Round 11
// baseline (225.345 us; speedup 1.0000x reference)
//
#include <hip/hip_runtime.h>
#include <hip/hip_bf16.h>

#define BATCH 16
#define NV    20000
#define FIN   64
#define NCOUT 64
#define NK    16
#define TOTROWS  (BATCH * NV)      // 320000
#define NTILES   (TOTROWS / 16)    // 20000 row-tiles of 16

typedef __attribute__((ext_vector_type(8))) short bf16x8;   // 8 bf16 (4 VGPRs)
typedef __attribute__((ext_vector_type(4))) float f32x4;    // MFMA acc
typedef __attribute__((ext_vector_type(4))) unsigned short u16x4;
typedef __attribute__((ext_vector_type(2))) unsigned int u32x2;

__device__ __forceinline__ short f2b(float f) {
    __hip_bfloat16 h = __float2bfloat16(f);   // RTNE
    return __builtin_bit_cast(short, h);
}

// ---------------------------------------------------------------------------
// Pass A: one x-sweep, MFMA 16x16x32 bf16.  (EXACT round-1 kernel — best
// measured config: grid 768, LB(256,3), prefetch pipeline, ~70 µs.)
//   p[row][c] = x[row]@Wx[:,c] + bias[c]  -> out (fp32)
//   z[row][c] = x[row]@(Wn/16)            -> ws  (bf16)
// ---------------------------------------------------------------------------
__global__ __launch_bounds__(256, 3) void convnet_gemm(
    const float* __restrict__ x,      // (320000, 64)
    const float* __restrict__ Wx,     // (64, 64)
    const float* __restrict__ Wn,     // (64, 64)
    const float* __restrict__ bias,   // (64)
    __hip_bfloat16* __restrict__ z,   // (320000, 64) bf16  [ws]
    float* __restrict__ out)          // (320000, 64) fp32  (gets p)
{
    const int lane = threadIdx.x & 63;
    const int m    = lane & 15;
    const int quad = lane >> 4;

    bf16x8 bf[8][2];
#pragma unroll
    for (int t = 0; t < 8; ++t) {
        const float* W = (t < 4) ? Wx : Wn;
        const float scale = (t < 4) ? 1.0f : (1.0f / 16.0f);
        const int c = 4 * m + (t & 3);
#pragma unroll
        for (int h = 0; h < 2; ++h) {
            bf16x8 fr;
#pragma unroll
            for (int j = 0; j < 8; ++j) {
                const int f = 32 * h + quad * 8 + j;
                fr[j] = f2b(W[f * NCOUT + c] * scale);
            }
            bf[t][h] = fr;
        }
    }
    float bias_q[4];
#pragma unroll
    for (int t = 0; t < 4; ++t) bias_q[t] = bias[4 * m + t];

    const int nwaves = (gridDim.x * blockDim.x) >> 6;   // 3072
    const int gw = (blockIdx.x * blockDim.x + threadIdx.x) >> 6;

    int rt = __builtin_amdgcn_readfirstlane(gw);
    const float* xt0 = x + (size_t)rt * (16 * FIN) + (size_t)m * FIN + quad * 8;
    float4 La0 = ((const float4*)xt0)[0];
    float4 La1 = ((const float4*)xt0)[1];
    float4 Lb0 = ((const float4*)(xt0 + 32))[0];
    float4 Lb1 = ((const float4*)(xt0 + 32))[1];

    for (;;) {
        bf16x8 af0, af1;
        af0[0] = f2b(La0.x); af0[1] = f2b(La0.y); af0[2] = f2b(La0.z); af0[3] = f2b(La0.w);
        af0[4] = f2b(La1.x); af0[5] = f2b(La1.y); af0[6] = f2b(La1.z); af0[7] = f2b(La1.w);
        af1[0] = f2b(Lb0.x); af1[1] = f2b(Lb0.y); af1[2] = f2b(Lb0.z); af1[3] = f2b(Lb0.w);
        af1[4] = f2b(Lb1.x); af1[5] = f2b(Lb1.y); af1[6] = f2b(Lb1.z); af1[7] = f2b(Lb1.w);

        const int rtn = rt + nwaves;
        const bool more = rtn < NTILES;
        float4 Na0, Na1, Nb0, Nb1;
        if (more) {
            const float* xn = x + (size_t)rtn * (16 * FIN) + (size_t)m * FIN + quad * 8;
            Na0 = ((const float4*)xn)[0];
            Na1 = ((const float4*)xn)[1];
            Nb0 = ((const float4*)(xn + 32))[0];
            Nb1 = ((const float4*)(xn + 32))[1];
        }

        f32x4 acc[8];
#pragma unroll
        for (int t = 0; t < 8; ++t) acc[t] = (f32x4){0.f, 0.f, 0.f, 0.f};
#pragma unroll
        for (int t = 0; t < 8; ++t)
            acc[t] = __builtin_amdgcn_mfma_f32_16x16x32_bf16(af0, bf[t][0], acc[t], 0, 0, 0);
#pragma unroll
        for (int t = 0; t < 8; ++t)
            acc[t] = __builtin_amdgcn_mfma_f32_16x16x32_bf16(af1, bf[t][1], acc[t], 0, 0, 0);

        const size_t rbase = (size_t)rt * 16 + quad * 4;
#pragma unroll
        for (int r = 0; r < 4; ++r) {
            const size_t orow = (rbase + r) * NCOUT + 4 * m;
            float4 o;
            o.x = acc[0][r] + bias_q[0];
            o.y = acc[1][r] + bias_q[1];
            o.z = acc[2][r] + bias_q[2];
            o.w = acc[3][r] + bias_q[3];
            *(float4*)(out + orow) = o;
            u16x4 zz;
            zz.x = (unsigned short)f2b(acc[4][r]);
            zz.y = (unsigned short)f2b(acc[5][r]);
            zz.z = (unsigned short)f2b(acc[6][r]);
            zz.w = (unsigned short)f2b(acc[7][r]);
            *(u16x4*)(z + orow) = zz;
        }

        if (!more) break;
        rt = __builtin_amdgcn_readfirstlane(rtn);
        La0 = Na0; La1 = Na1; Lb0 = Nb0; Lb1 = Nb1;
    }
}

// ---------------------------------------------------------------------------
// Pass B: out[b,v,:] += sum_k z[b, nbr[v,k]-1, :]  (idx==0 = zero pad).
// Base = EXACT round-2 shape/config (z fetched 1.0x, WRITE=80, 72 µs):
// wave = 4 rows, lane = (s=lane>>4, c=lane&15), dwordx2 gathers, one
// contiguous f32x4 store/lane, grid 1536, plain (cached) loads/stores.
// ROUND-11 SINGLE LEVER: TWO groups (g and g+WPX) per loop iteration.
// r2 proved the limiter is the serial nbr->gather dependency chain (ideal
// traffic, 2.8 TB/s, all pipes <50%); r8 proved the pattern sustains ~4 TB/s
// given enough requests in flight. Pairing doubles per-wave MLP (2 out-reads
// + 8 nbr loads + 32 gathers outstanding) at constant occupancy/footprint.
// LB(256,4): 128-VGPR cap comfortably fits the ~70-reg paired body.
// ---------------------------------------------------------------------------
__global__ __launch_bounds__(256, 4) void convnet_gather(
    const int* __restrict__ nbr,           // (20000, 16), values in [0, V]
    const __hip_bfloat16* __restrict__ z,  // (320000, 64) bf16
    float* __restrict__ out)               // (320000, 64) fp32, has p already
{
    const int lane = threadIdx.x & 63;
    const int s    = lane >> 4;            // sub-row 0..3
    const int c    = lane & 15;            // col group (4 bf16 = 8 B)
    const int xcd  = blockIdx.x & 7;
    const int bi   = blockIdx.x >> 3;                        // 0..191
    const int wl   = bi * 4 + ((int)threadIdx.x >> 6);       // 0..767
    const int WPX  = (gridDim.x >> 3) * 4;                   // 768 waves/xcd

    const int zcol   = c * 8;              // byte col offset (4 bf16)
    const int GROUPS = (2 * NV) / 4;       // 10000 groups per xcd

    for (int g = wl; g < GROUPS; g += 2 * WPX) {
        const int gA = __builtin_amdgcn_readfirstlane(g);
        const int has2 = (gA + WPX) < GROUPS;
        const int gB = __builtin_amdgcn_readfirstlane(has2 ? (gA + WPX) : gA);

        // ---- group A addresses + early loads
        const int blA = (gA >= NV / 4) ? 1 : 0;
        const int bA  = 2 * xcd + blA;
        const int vA  = gA * 4 - blA * NV;
        f32x4* opA = (f32x4*)(out + (size_t)(bA * NV + vA + s) * NCOUT + 4 * c);
        f32x4 ovA = *opA;
        const int4* nbA =
            (const int4*)((const char*)nbr + (size_t)(vA + s) * (NK * 4));
        const int4 a0v = nbA[0];
        const int4 a1v = nbA[1];
        const int4 a2v = nbA[2];
        const int4 a3v = nbA[3];

        // ---- group B addresses + early loads (same last group if tail)
        const int blB = (gB >= NV / 4) ? 1 : 0;
        const int bB  = 2 * xcd + blB;
        const int vB  = gB * 4 - blB * NV;
        f32x4* opB = (f32x4*)(out + (size_t)(bB * NV + vB + s) * NCOUT + 4 * c);
        f32x4 ovB = *opB;
        const int4* nbB =
            (const int4*)((const char*)nbr + (size_t)(vB + s) * (NK * 4));
        const int4 b0v = nbB[0];
        const int4 b1v = nbB[1];
        const int4 b2v = nbB[2];
        const int4 b3v = nbB[3];

        const char* zbA = (const char*)z + (size_t)bA * (NV * 128);
        const char* zbB = (const char*)z + (size_t)bB * (NV * 128);

        int idA[NK], idB[NK];
        idA[0]  = a0v.x; idA[1]  = a0v.y; idA[2]  = a0v.z; idA[3]  = a0v.w;
        idA[4]  = a1v.x; idA[5]  = a1v.y; idA[6]  = a1v.z; idA[7]  = a1v.w;
        idA[8]  = a2v.x; idA[9]  = a2v.y; idA[10] = a2v.z; idA[11] = a2v.w;
        idA[12] = a3v.x; idA[13] = a3v.y; idA[14] = a3v.z; idA[15] = a3v.w;
        idB[0]  = b0v.x; idB[1]  = b0v.y; idB[2]  = b0v.z; idB[3]  = b0v.w;
        idB[4]  = b1v.x; idB[5]  = b1v.y; idB[6]  = b1v.z; idB[7]  = b1v.w;
        idB[8]  = b2v.x; idB[9]  = b2v.y; idB[10] = b2v.z; idB[11] = b2v.w;
        idB[12] = b3v.x; idB[13] = b3v.y; idB[14] = b3v.z; idB[15] = b3v.w;

        float aA0 = 0.f, aA1 = 0.f, aA2 = 0.f, aA3 = 0.f;
        float aB0 = 0.f, aB1 = 0.f, aB2 = 0.f, aB3 = 0.f;
#pragma unroll
        for (int k = 0; k < NK; ++k) {
            const int ixA = idA[k];
            int selA = ixA - 1;
            selA = selA < 0 ? 0 : selA;
            const u32x2 dA =
                *(const u32x2*)(zbA + (size_t)(unsigned)(selA * 128 + zcol));
            const int ixB = idB[k];
            int selB = ixB - 1;
            selB = selB < 0 ? 0 : selB;
            const u32x2 dB =
                *(const u32x2*)(zbB + (size_t)(unsigned)(selB * 128 + zcol));

            const unsigned dAx = ixA ? dA.x : 0u;
            const unsigned dAy = ixA ? dA.y : 0u;
            aA0 += __builtin_bit_cast(float, dAx << 16);
            aA1 += __builtin_bit_cast(float, dAx & 0xFFFF0000u);
            aA2 += __builtin_bit_cast(float, dAy << 16);
            aA3 += __builtin_bit_cast(float, dAy & 0xFFFF0000u);
            const unsigned dBx = ixB ? dB.x : 0u;
            const unsigned dBy = ixB ? dB.y : 0u;
            aB0 += __builtin_bit_cast(float, dBx << 16);
            aB1 += __builtin_bit_cast(float, dBx & 0xFFFF0000u);
            aB2 += __builtin_bit_cast(float, dBy << 16);
            aB3 += __builtin_bit_cast(float, dBy & 0xFFFF0000u);
        }

        ovA.x += aA0; ovA.y += aA1; ovA.z += aA2; ovA.w += aA3;
        *opA = ovA;
        if (has2) {
            ovB.x += aB0; ovB.y += aB1; ovB.z += aB2; ovB.w += aB3;
            *opB = ovB;
        }
    }
}

extern "C" void kernel_launch(void* const* d_in, const int* in_sizes, int n_in,
                              void* d_out, int out_size, void* d_ws, size_t ws_size,
                              hipStream_t stream) {
    const float* x    = (const float*)d_in[0];
    const float* Wx   = (const float*)d_in[1];
    const float* Wn   = (const float*)d_in[2];
    const float* bias = (const float*)d_in[3];
    const int*   nbr  = (const int*)d_in[4];
    float* out = (float*)d_out;

    __hip_bfloat16* z = (__hip_bfloat16*)d_ws;   // 40.96 MB (fits ws)

    hipLaunchKernelGGL(convnet_gemm, dim3(768), dim3(256), 0, stream,
                       x, Wx, Wn, bias, z, out);
    hipLaunchKernelGGL(convnet_gather, dim3(1536), dim3(256), 0, stream,
                       nbr, z, out);
}